// Round 6
// baseline (41.748 us; speedup 1.0000x reference)
//
#include <hip/hip_runtime.h>
#include <math.h>

#define W_ 128
#define H_ 96
#define C_ 128
#define HW_ (H_ * W_)          // 12288
#define K_ 81
#define FLOW_ELEMS (2 * 2 * H_ * W_)   // 49152

// Corr kernel, dy-sliced: one 64-thread block (= one wave) per (b, y0, dg),
// dg in 0..8 -> dy = dg-4. The wave accumulates ALL 128 channels for its single
// halo row r = y0+dg-4 and writes the disjoint k-slice [dg*9, dg*9+9) of corr
// for all 128 pixels of row y0. No cross-wave reduction anywhere.
// Round 6: one-chunk-ahead register prefetch (T14) with named A/B buffers.
// Lane owns pixels x = 2*lane, 2*lane+1. Grid = 1728 blocks (8 XCD chunks x 216).
__global__ __launch_bounds__(64) void corr_kernel(const float* __restrict__ f0,
                                                  const float* __restrict__ f1,
                                                  float* __restrict__ corr) {
    __shared__ float lds[8][136];   // 8-channel chunk of the halo row (4352 B)

    const int lane = threadIdx.x;

    // XCD-bijective swizzle: 1728 = 8 * 216; the 9 dy-waves of a row stay on one XCD
    const int L = (blockIdx.x & 7) * 216 + (blockIdx.x >> 3);
    const int dg = L % 9;
    const int rid = L / 9;               // 0..191
    const int y0 = rid % H_;
    const int b  = rid / H_;
    const int r  = y0 + dg - 4;          // halo row in f1 (may be OOB)
    const bool rok = (r >= 0) && (r < H_);

    // staging: lane q stages quad q covering f1 columns q*4-4 .. q*4-1;
    // LDS word w holds column w-4. Quads 0 and 33 are fully OOB -> zeros.
    const int q = lane;
    const bool qok = rok && (q >= 1) && (q <= 32);
    const float* f0p = f0 + (size_t)b * C_ * HW_ + (size_t)y0 * W_ + 2 * lane;
    const float* f1p = f1 + (size_t)b * C_ * HW_ + (size_t)(rok ? r : 0) * W_ + (q * 4 - 4);

    float acc0[9], acc1[9];
#pragma unroll
    for (int j = 0; j < 9; ++j) { acc0[j] = 0.f; acc1[j] = 0.f; }

    // ---- load chunk ck (8 channels) into named register set ----
    auto LOAD = [&](int ck, float4 (&v)[8], float2 (&g)[8]) {
#pragma unroll
        for (int cc = 0; cc < 8; ++cc) {
            const size_t co = (size_t)(ck * 8 + cc) * HW_;
            g[cc] = *(const float2*)(f0p + co);
            float4 t = make_float4(0.f, 0.f, 0.f, 0.f);
            if (qok) t = *(const float4*)(f1p + co);
            v[cc] = t;
        }
    };

    // ---- stage to LDS and accumulate 18 FMA per channel per lane ----
    auto CONSUME = [&](const float4 (&v)[8], const float2 (&g)[8]) {
        __syncthreads();                 // WAR: previous chunk's reads complete
        if (q < 34) {
#pragma unroll
            for (int cc = 0; cc < 8; ++cc)
                *(float4*)&lds[cc][q * 4] = v[cc];
        }
        __syncthreads();                 // RAW: writes visible to all lanes
#pragma unroll
        for (int cc = 0; cc < 8; ++cc) {
            const float2* row = (const float2*)(&lds[cc][0]) + lane;
            const float2 w0 = row[0], w1 = row[1], w2 = row[2],
                         w3 = row[3], w4 = row[4];
            const float vv[10] = {w0.x, w0.y, w1.x, w1.y, w2.x,
                                  w2.y, w3.x, w3.y, w4.x, w4.y};
#pragma unroll
            for (int dx = 0; dx < 9; ++dx) {
                acc0[dx] += g[cc].x * vv[dx];
                acc1[dx] += g[cc].y * vv[dx + 1];
            }
        }
    };

    float4 vA[8], vB[8];
    float2 gA[8], gB[8];

    // chunk coverage: A consumes 0,2,...,14; B consumes 1,3,...,15.
    LOAD(0, vA, gA);
    for (int it = 0; it < 8; ++it) {
        LOAD(2 * it + 1, vB, gB);        // prefetch odd chunk
        CONSUME(vA, gA);                 // consume even chunk (loads for B in flight)
        if (it < 7) LOAD(2 * it + 2, vA, gA);   // prefetch next even chunk
        CONSUME(vB, gB);                 // consume odd chunk (loads for A in flight)
    }

    // disjoint k-slice writeout; OOB-row waves naturally wrote acc==0
    float* cb = corr + ((size_t)b * HW_ + (size_t)y0 * W_ + 2 * lane) * K_ + dg * 9;
#pragma unroll
    for (int j = 0; j < 9; ++j) cb[j] = acc0[j];
#pragma unroll
    for (int j = 0; j < 9; ++j) cb[K_ + j] = acc1[j];
}

// Kernel 2: scale by 1/sqrt(128), softmax over K in-place, prob + flow.
__global__ __launch_bounds__(256) void softmax_kernel(float* __restrict__ out) {
    const int t = threadIdx.x;
    const int wave = t >> 6, lane = t & 63;
    const int px = (blockIdx.x << 2) + wave;      // 0 .. 24575
    const int b = px / HW_;
    const int pl = px - b * HW_;
    const int y = pl >> 7, x = pl & 127;

    float* corr = out + FLOW_ELEMS + (size_t)px * K_;
    const float scale = 0.08838834764831845f;     // 1/sqrt(128)

    const bool has1 = lane < (K_ - 64);           // lane < 17
    float v0 = corr[lane] * scale;
    float v1 = has1 ? corr[lane + 64] * scale : -1e30f;

    float m = fmaxf(v0, v1);
#pragma unroll
    for (int off = 32; off; off >>= 1) m = fmaxf(m, __shfl_xor(m, off));

    float e0 = __expf(v0 - m);
    float e1 = has1 ? __expf(v1 - m) : 0.f;
    float s = e0 + e1;
#pragma unroll
    for (int off = 32; off; off >>= 1) s += __shfl_xor(s, off);

    const float inv = 1.f / s;
    const float p0 = e0 * inv;
    const float p1 = e1 * inv;

    corr[lane] = p0;
    if (has1) corr[lane + 64] = p1;

    float fx = p0 * (float)(lane % 9 - 4) + p1 * (float)((lane + 64) % 9 - 4);
    float fy = p0 * (float)(lane / 9 - 4) + p1 * (float)((lane + 64) / 9 - 4);
#pragma unroll
    for (int off = 32; off; off >>= 1) {
        fx += __shfl_xor(fx, off);
        fy += __shfl_xor(fy, off);
    }

    if (lane == 0) {
        out[((size_t)(b * 2 + 0) * H_ + y) * W_ + x] = fx;
        out[((size_t)(b * 2 + 1) * H_ + y) * W_ + x] = fy;
    }
}

extern "C" void kernel_launch(void* const* d_in, const int* in_sizes, int n_in,
                              void* d_out, int out_size, void* d_ws, size_t ws_size,
                              hipStream_t stream) {
    (void)in_sizes; (void)n_in; (void)d_ws; (void)ws_size; (void)out_size;
    const float* f0 = (const float*)d_in[0];
    const float* f1 = (const float*)d_in[1];
    float* out = (float*)d_out;

    corr_kernel<<<1728, 64, 0, stream>>>(f0, f1, out + FLOW_ELEMS);
    softmax_kernel<<<6144, 256, 0, stream>>>(out);
}

// Round 7
// 41.591 us; speedup vs baseline: 1.0038x; 1.0038x over previous
//
#include <hip/hip_runtime.h>
#include <math.h>

#define W_ 128
#define H_ 96
#define C_ 128
#define HW_ (H_ * W_)          // 12288
#define K_ 81
#define FLOW_ELEMS (2 * 2 * H_ * W_)   // 49152

// Corr kernel, dy-sliced: one 64-thread block (= one wave) per (b, y0, dg),
// dg in 0..8 -> dy = dg-4. The wave accumulates ALL 128 channels for its single
// halo row r = y0+dg-4 and writes the disjoint k-slice [dg*9, dg*9+9) of corr
// for all 128 pixels of row y0. No cross-wave reduction anywhere.
// Round 7: NO __syncthreads (1-wave block; same-wave DS-pipe order is sufficient,
// validated in R1). __builtin_amdgcn_sched_barrier(0) pins compiler ordering
// around the LDS writes without emitting any runtime vmcnt drain -> the A/B
// register prefetch actually stays in flight across the consume phase.
// Lane owns pixels x = 2*lane, 2*lane+1. Grid = 1728 blocks (8 XCD chunks x 216).
__global__ __launch_bounds__(64) void corr_kernel(const float* __restrict__ f0,
                                                  const float* __restrict__ f1,
                                                  float* __restrict__ corr) {
    __shared__ float lds[8][136];   // 8-channel chunk of the halo row (4352 B)

    const int lane = threadIdx.x;

    // XCD-bijective swizzle: 1728 = 8 * 216; the 9 dy-waves of a row stay on one XCD
    const int L = (blockIdx.x & 7) * 216 + (blockIdx.x >> 3);
    const int dg = L % 9;
    const int rid = L / 9;               // 0..191
    const int y0 = rid % H_;
    const int b  = rid / H_;
    const int r  = y0 + dg - 4;          // halo row in f1 (may be OOB)
    const bool rok = (r >= 0) && (r < H_);

    // staging: lane q stages quad q covering f1 columns q*4-4 .. q*4-1;
    // LDS word w holds column w-4. Quads 0 and 33 are fully OOB -> zeros.
    const int q = lane;
    const bool qok = rok && (q >= 1) && (q <= 32);
    const float* f0p = f0 + (size_t)b * C_ * HW_ + (size_t)y0 * W_ + 2 * lane;
    const float* f1p = f1 + (size_t)b * C_ * HW_ + (size_t)(rok ? r : 0) * W_ + (q * 4 - 4);

    float acc0[9], acc1[9];
#pragma unroll
    for (int j = 0; j < 9; ++j) { acc0[j] = 0.f; acc1[j] = 0.f; }

    // ---- load chunk ck (8 channels) into named register set ----
    auto LOAD = [&](int ck, float4 (&v)[8], float2 (&g)[8]) {
#pragma unroll
        for (int cc = 0; cc < 8; ++cc) {
            const size_t co = (size_t)(ck * 8 + cc) * HW_;
            g[cc] = *(const float2*)(f0p + co);
            float4 t = make_float4(0.f, 0.f, 0.f, 0.f);
            if (qok) t = *(const float4*)(f1p + co);
            v[cc] = t;
        }
    };

    // ---- stage to LDS (compiler-fenced, no runtime barrier) and accumulate ----
    auto CONSUME = [&](const float4 (&v)[8], const float2 (&g)[8]) {
        // fence: previous chunk's ds_reads may not sink below the writes (WAR),
        // and the writes may not sink below the reads issued after (RAW).
        __builtin_amdgcn_sched_barrier(0);
        if (q < 34) {
#pragma unroll
            for (int cc = 0; cc < 8; ++cc)
                *(float4*)&lds[cc][q * 4] = v[cc];
        }
        __builtin_amdgcn_sched_barrier(0);
        // same-wave DS-pipe order: reads issued after writes see the new data
#pragma unroll
        for (int cc = 0; cc < 8; ++cc) {
            const float2* row = (const float2*)(&lds[cc][0]) + lane;
            const float2 w0 = row[0], w1 = row[1], w2 = row[2],
                         w3 = row[3], w4 = row[4];
            const float vv[10] = {w0.x, w0.y, w1.x, w1.y, w2.x,
                                  w2.y, w3.x, w3.y, w4.x, w4.y};
#pragma unroll
            for (int dx = 0; dx < 9; ++dx) {
                acc0[dx] += g[cc].x * vv[dx];
                acc1[dx] += g[cc].y * vv[dx + 1];
            }
        }
    };

    float4 vA[8], vB[8];
    float2 gA[8], gB[8];

    // chunk coverage: A consumes 0,2,...,14; B consumes 1,3,...,15.
    LOAD(0, vA, gA);
    for (int it = 0; it < 8; ++it) {
        LOAD(2 * it + 1, vB, gB);        // prefetch odd chunk (stays in flight)
        CONSUME(vA, gA);                 // counted vmcnt wait: only A's regs
        if (it < 7) LOAD(2 * it + 2, vA, gA);   // prefetch next even chunk
        CONSUME(vB, gB);
    }

    // disjoint k-slice writeout; OOB-row waves naturally wrote acc==0
    float* cb = corr + ((size_t)b * HW_ + (size_t)y0 * W_ + 2 * lane) * K_ + dg * 9;
#pragma unroll
    for (int j = 0; j < 9; ++j) cb[j] = acc0[j];
#pragma unroll
    for (int j = 0; j < 9; ++j) cb[K_ + j] = acc1[j];
}

// Kernel 2: scale by 1/sqrt(128), softmax over K in-place, prob + flow.
__global__ __launch_bounds__(256) void softmax_kernel(float* __restrict__ out) {
    const int t = threadIdx.x;
    const int wave = t >> 6, lane = t & 63;
    const int px = (blockIdx.x << 2) + wave;      // 0 .. 24575
    const int b = px / HW_;
    const int pl = px - b * HW_;
    const int y = pl >> 7, x = pl & 127;

    float* corr = out + FLOW_ELEMS + (size_t)px * K_;
    const float scale = 0.08838834764831845f;     // 1/sqrt(128)

    const bool has1 = lane < (K_ - 64);           // lane < 17
    float v0 = corr[lane] * scale;
    float v1 = has1 ? corr[lane + 64] * scale : -1e30f;

    float m = fmaxf(v0, v1);
#pragma unroll
    for (int off = 32; off; off >>= 1) m = fmaxf(m, __shfl_xor(m, off));

    float e0 = __expf(v0 - m);
    float e1 = has1 ? __expf(v1 - m) : 0.f;
    float s = e0 + e1;
#pragma unroll
    for (int off = 32; off; off >>= 1) s += __shfl_xor(s, off);

    const float inv = 1.f / s;
    const float p0 = e0 * inv;
    const float p1 = e1 * inv;

    corr[lane] = p0;
    if (has1) corr[lane + 64] = p1;

    float fx = p0 * (float)(lane % 9 - 4) + p1 * (float)((lane + 64) % 9 - 4);
    float fy = p0 * (float)(lane / 9 - 4) + p1 * (float)((lane + 64) / 9 - 4);
#pragma unroll
    for (int off = 32; off; off >>= 1) {
        fx += __shfl_xor(fx, off);
        fy += __shfl_xor(fy, off);
    }

    if (lane == 0) {
        out[((size_t)(b * 2 + 0) * H_ + y) * W_ + x] = fx;
        out[((size_t)(b * 2 + 1) * H_ + y) * W_ + x] = fy;
    }
}

extern "C" void kernel_launch(void* const* d_in, const int* in_sizes, int n_in,
                              void* d_out, int out_size, void* d_ws, size_t ws_size,
                              hipStream_t stream) {
    (void)in_sizes; (void)n_in; (void)d_ws; (void)ws_size; (void)out_size;
    const float* f0 = (const float*)d_in[0];
    const float* f1 = (const float*)d_in[1];
    float* out = (float*)d_out;

    corr_kernel<<<1728, 64, 0, stream>>>(f0, f1, out + FLOW_ELEMS);
    softmax_kernel<<<6144, 256, 0, stream>>>(out);
}